// Round 2
// baseline (975.637 us; speedup 1.0000x reference)
//
#include <hip/hip_runtime.h>
#include <stdint.h>

#define H 4096
#define KSEL 410
#define NT 256

__device__ __forceinline__ uint32_t absbits(float f) {
  return __float_as_uint(f) & 0x7fffffffu;
}

__global__ __launch_bounds__(NT) void topk_select_kernel(
    const float* __restrict__ x, float* __restrict__ out) {
  // smem[0..2304): padded 2048-bin histogram (bin b lives at b + (b>>3)).
  // After the scan it is reused as the candidate buffer smem[0..4096)
  // (worst case = whole row in one bin, so always safe).
  __shared__ uint32_t smem[4096];
  __shared__ uint32_t aux[NT];
  __shared__ uint32_t s_bin, s_k, s_cnt, s_ccnt;
  __shared__ uint32_t s_t, s_e, s_kk;

  const int tid = threadIdx.x;
  const size_t base = (size_t)blockIdx.x * H;
  const float4* __restrict__ xr = (const float4*)(x + base);

  // coalesced load: thread t owns float4s {t, t+256, t+512, t+768}
  float4 r[4];
  #pragma unroll
  for (int j = 0; j < 4; ++j) r[j] = xr[tid + j * NT];

  uint32_t u[16];
  #pragma unroll
  for (int j = 0; j < 4; ++j) {
    u[4*j+0] = absbits(r[j].x);
    u[4*j+1] = absbits(r[j].y);
    u[4*j+2] = absbits(r[j].z);
    u[4*j+3] = absbits(r[j].w);
  }

  // ---- zero histogram (2304 words) + candidate counter ----
  #pragma unroll
  for (int j = 0; j < 9; ++j) smem[tid + j * NT] = 0;
  if (tid == 0) s_ccnt = 0;
  __syncthreads();

  // ---- single 2048-bin histogram over bits [30:20] (exp + 3 mantissa) ----
  // No prefix test needed: every element participates in round 0.
  #pragma unroll
  for (int j = 0; j < 16; ++j) {
    const uint32_t b = u[j] >> 20;              // 0..2047
    atomicAdd(&smem[b + (b >> 3)], 1u);         // padded: tid*9+j layout
  }
  __syncthreads();

  // ---- per-thread local suffix sums over its 8 contiguous bins ----
  // padded stride 9 -> conflict-free lane access pattern
  uint32_t loc[8];
  {
    uint32_t sum = 0;
    #pragma unroll
    for (int j = 7; j >= 0; --j) {
      sum += smem[tid * 9 + j];
      loc[j] = sum;
    }
    aux[tid] = sum;
  }
  __syncthreads();

  // ---- wave 0: aux[t] := sum over all t' > t (suffix-exclusive) ----
  if (tid < 64) {
    uint4 a = ((const uint4*)aux)[tid];
    const uint32_t lsum = a.x + a.y + a.z + a.w;
    uint32_t s = lsum;
    #pragma unroll
    for (int off = 1; off < 64; off <<= 1) {
      uint32_t t = __shfl_down(s, off, 64);
      if (tid + off < 64) s += t;
    }
    const uint32_t above = s - lsum;
    uint4 o;
    o.x = above + a.y + a.z + a.w;
    o.y = above + a.z + a.w;
    o.z = above + a.w;
    o.w = above;
    ((uint4*)aux)[tid] = o;
  }
  __syncthreads();

  // ---- find the bin whose suffix range crosses rank KSEL ----
  {
    const uint32_t above_t = aux[tid];
    #pragma unroll
    for (int j = 0; j < 8; ++j) {
      const uint32_t s_incl = above_t + loc[j];
      const uint32_t s_abv  = (j < 7) ? (above_t + loc[j + 1]) : above_t;
      if (s_incl >= KSEL && s_abv < KSEL) {
        s_bin = (uint32_t)(tid * 8 + j);
        s_k   = KSEL - s_abv;        // rank of target within this bin
        s_cnt = s_incl - s_abv;      // bin population
      }
    }
  }
  __syncthreads();

  const uint32_t p  = s_bin;   // selected 11-bit prefix
  const uint32_t kk = s_k;     // 1-based rank within the bin
  const uint32_t c  = s_cnt;   // candidates in the bin

  // ---- compact candidates (values only) into smem[0..c) ----
  // hist region is dead now; ~c (~100) same-address atomics, cheap.
  #pragma unroll
  for (int j = 0; j < 16; ++j) {
    if ((u[j] >> 20) == p) {
      const uint32_t pos = atomicAdd(&s_ccnt, 1u);
      smem[pos] = u[j];
    }
  }
  __syncthreads();

  // ---- exact rank-count among candidates: find kk-th largest value ----
  // Each thread ranks only its own candidates; all active lanes read the
  // same LDS address per iteration (broadcast, conflict-free).
  #pragma unroll
  for (int j = 0; j < 16; ++j) {
    if ((u[j] >> 20) == p) {
      const uint32_t v = u[j];
      uint32_t g = 0, e = 0;
      for (uint32_t i = 0; i < c; ++i) {
        const uint32_t cv = smem[i];
        g += (cv > v) ? 1u : 0u;
        e += (cv == v) ? 1u : 0u;
      }
      if (g < kk && kk <= g + e) {   // v is the KSEL-th largest |x|
        s_t  = v;                    // threshold bits
        s_e  = e;                    // how many == threshold exist
        s_kk = kk - g;               // how many == threshold to keep
      }
    }
  }
  __syncthreads();

  const uint32_t tbits   = s_t;
  const uint32_t cnt_eq  = s_e;
  const uint32_t keep_eq = s_kk;

  uint32_t cut = H;                  // default: keep every equal element
  if (cnt_eq != keep_eq) {
    // rare exact tie at the boundary: find index of the keep_eq-th equal
    if (tid == 0) {
      const float* xs = x + base;
      uint32_t cg = 0, ct = H;
      for (int i = 0; i < H; ++i) {
        if (absbits(xs[i]) == tbits) {
          if (++cg == keep_eq) { ct = (uint32_t)i; break; }
        }
      }
      s_bin = ct;
    }
    __syncthreads();
    cut = s_bin;
  }

  // ---- masked write-back, coalesced float4 ----
  float4* __restrict__ outr = (float4*)(out + base);
  #pragma unroll
  for (int j = 0; j < 4; ++j) {
    const float4 v = r[j];
    const uint32_t i0 = 4u * (uint32_t)(tid + j * NT);
    float4 o;
    o.x = (u[4*j+0] > tbits || (u[4*j+0] == tbits && i0 + 0u <= cut)) ? v.x : 0.0f;
    o.y = (u[4*j+1] > tbits || (u[4*j+1] == tbits && i0 + 1u <= cut)) ? v.y : 0.0f;
    o.z = (u[4*j+2] > tbits || (u[4*j+2] == tbits && i0 + 2u <= cut)) ? v.z : 0.0f;
    o.w = (u[4*j+3] > tbits || (u[4*j+3] == tbits && i0 + 3u <= cut)) ? v.w : 0.0f;
    outr[tid + j * NT] = o;
  }
}

extern "C" void kernel_launch(void* const* d_in, const int* in_sizes, int n_in,
                              void* d_out, int out_size, void* d_ws, size_t ws_size,
                              hipStream_t stream) {
  const float* x = (const float*)d_in[0];
  float* out = (float*)d_out;
  const int rows = in_sizes[0] / H;   // 16384
  hipLaunchKernelGGL(topk_select_kernel, dim3(rows), dim3(NT), 0, stream, x, out);
}

// Round 3
// 434.607 us; speedup vs baseline: 2.2449x; 2.2449x over previous
//
#include <hip/hip_runtime.h>
#include <stdint.h>

#define H 4096
#define KSEL 410
#define NT 256
#define NBIN 8192                 // 13-bit bins: absbits >> 18
#define BPT (NBIN / NT)           // 32 bins per thread
#define PADW (NBIN + 4 * (NBIN / 32))  // 9216 padded words
// bin b lives at A(b) = b + 4*(b>>5); thread t owns bins [32t,32t+32)
// at contiguous addresses [36t, 36t+32) -> conflict-free scans, 16B-aligned.

__device__ __forceinline__ uint32_t absbits(float f) {
  return __float_as_uint(f) & 0x7fffffffu;
}

__global__ __launch_bounds__(NT) void topk_select_kernel(
    const float* __restrict__ x, float* __restrict__ out) {
  __shared__ uint32_t smem[PADW];   // histogram, then candidate buffer
  __shared__ uint32_t aux[NT];
  __shared__ uint32_t s_bin, s_k, s_cnt, s_ccnt;
  __shared__ uint32_t s_t, s_e, s_kk, s_cut;

  const int tid = threadIdx.x;
  const size_t base = (size_t)blockIdx.x * H;
  const float4* __restrict__ xr = (const float4*)(x + base);

  // ---- load row: thread t owns float4s {t, t+256, t+512, t+768} ----
  float4 r[4];
  #pragma unroll
  for (int j = 0; j < 4; ++j) r[j] = xr[tid + j * NT];

  uint32_t u[16];
  #pragma unroll
  for (int j = 0; j < 4; ++j) {
    u[4*j+0] = absbits(r[j].x);
    u[4*j+1] = absbits(r[j].y);
    u[4*j+2] = absbits(r[j].z);
    u[4*j+3] = absbits(r[j].w);
  }

  // ---- zero histogram (vectorized) ----
  {
    uint4* s4 = (uint4*)smem;
    const uint4 z = {0u, 0u, 0u, 0u};
    for (int i = tid; i < PADW / 4; i += NT) s4[i] = z;
  }
  if (tid == 0) s_ccnt = 0;
  __syncthreads();

  // ---- 8192-bin histogram over bits [30:18] ----
  #pragma unroll
  for (int j = 0; j < 16; ++j) {
    const uint32_t b = u[j] >> 18;
    atomicAdd(&smem[b + 4u * (b >> 5)], 1u);
  }
  __syncthreads();

  // ---- per-thread bin-sum (b128 reads, conflict-tolerable) ----
  uint32_t lsum = 0;
  {
    const uint4* s4 = (const uint4*)(smem + 36 * tid);
    #pragma unroll
    for (int j = 0; j < 8; ++j) {
      const uint4 a = s4[j];
      lsum += a.x + a.y + a.z + a.w;
    }
    aux[tid] = lsum;
  }
  __syncthreads();

  // ---- wave 0: aux[t] := sum over all t' > t (suffix-exclusive) ----
  if (tid < 64) {
    uint4 a = ((const uint4*)aux)[tid];
    const uint32_t l4 = a.x + a.y + a.z + a.w;
    uint32_t s = l4;
    #pragma unroll
    for (int off = 1; off < 64; off <<= 1) {
      uint32_t t = __shfl_down(s, off, 64);
      if (tid + off < 64) s += t;
    }
    const uint32_t above = s - l4;
    uint4 o;
    o.x = above + a.y + a.z + a.w;
    o.y = above + a.z + a.w;
    o.z = above + a.w;
    o.w = above;
    ((uint4*)aux)[tid] = o;
  }
  __syncthreads();

  // ---- exactly one thread's bin range crosses rank KSEL; it finds the bin ----
  {
    const uint32_t above_t = aux[tid];
    if (above_t < KSEL && KSEL <= above_t + lsum) {
      uint32_t cum = above_t;
      for (int j = BPT - 1; j >= 0; --j) {
        const uint32_t cj = smem[36 * tid + j];
        if (cum < KSEL && KSEL <= cum + cj) {
          s_bin = (uint32_t)(32 * tid + j);
          s_k   = KSEL - cum;     // rank of target within this bin
          s_cnt = cj;             // bin population
        }
        cum += cj;
      }
    }
  }
  __syncthreads();

  const uint32_t p = s_bin;       // selected 13-bit prefix
  const uint32_t c = s_cnt;       // candidate count (~31 expected)

  // ---- compact candidate values into smem[0..c) (hist region is dead) ----
  #pragma unroll
  for (int j = 0; j < 16; ++j) {
    if ((u[j] >> 18) == p) {
      const uint32_t pos = atomicAdd(&s_ccnt, 1u);
      smem[pos] = u[j];
    }
  }
  __syncthreads();

  // ---- wave 0: rank candidates (chunked, handles any c; usually 1 chunk) ----
  if (tid < 64) {
    const uint32_t kk = s_k;
    for (uint32_t b0 = 0; b0 < c; b0 += 64) {
      const uint32_t idx = b0 + (uint32_t)tid;
      if (idx < c) {
        const uint32_t v = smem[idx];
        uint32_t g = 0, e = 0;
        for (uint32_t i = 0; i < c; ++i) {   // LDS broadcast reads
          const uint32_t cv = smem[i];
          g += (cv > v) ? 1u : 0u;
          e += (cv == v) ? 1u : 0u;
        }
        if (g < kk && kk <= g + e) {         // v is the KSEL-th largest |x|
          s_t  = v;
          s_e  = e;
          s_kk = kk - g;
        }
      }
    }
  }
  __syncthreads();

  const uint32_t tbits   = s_t;
  const uint32_t cnt_eq  = s_e;
  const uint32_t keep_eq = s_kk;

  uint32_t cut = H;               // default: keep every ==tbits element
  if (cnt_eq != keep_eq) {        // rare boundary tie: earliest-index rule
    if (tid == 0) {
      const float* xs = x + base;
      uint32_t cg = 0, ct = H;
      for (int i = 0; i < H; ++i) {
        if (absbits(xs[i]) == tbits) {
          if (++cg == keep_eq) { ct = (uint32_t)i; break; }
        }
      }
      s_cut = ct;
    }
    __syncthreads();
    cut = s_cut;
  }

  // ---- masked write-back, coalesced float4 ----
  float4* __restrict__ outr = (float4*)(out + base);
  #pragma unroll
  for (int j = 0; j < 4; ++j) {
    const float4 v = r[j];
    const uint32_t i0 = 4u * (uint32_t)(tid + j * NT);
    float4 o;
    o.x = (u[4*j+0] > tbits || (u[4*j+0] == tbits && i0 + 0u <= cut)) ? v.x : 0.0f;
    o.y = (u[4*j+1] > tbits || (u[4*j+1] == tbits && i0 + 1u <= cut)) ? v.y : 0.0f;
    o.z = (u[4*j+2] > tbits || (u[4*j+2] == tbits && i0 + 2u <= cut)) ? v.z : 0.0f;
    o.w = (u[4*j+3] > tbits || (u[4*j+3] == tbits && i0 + 3u <= cut)) ? v.w : 0.0f;
    outr[tid + j * NT] = o;
  }
}

extern "C" void kernel_launch(void* const* d_in, const int* in_sizes, int n_in,
                              void* d_out, int out_size, void* d_ws, size_t ws_size,
                              hipStream_t stream) {
  const float* x = (const float*)d_in[0];
  float* out = (float*)d_out;
  const int rows = in_sizes[0] / H;   // 16384
  hipLaunchKernelGGL(topk_select_kernel, dim3(rows), dim3(NT), 0, stream, x, out);
}